// Round 7
// baseline (1810.250 us; speedup 1.0000x reference)
//
#include <hip/hip_runtime.h>
#include <hip/hip_bf16.h>
#include <stdint.h>

#define NN      50000
#define MMN     12
#define NMROWS  600000
#define ORIGF   92
#define NBRF    41
#define AFD     64
#define GCH     128
#define KTOT    169
#define BBC     500
#define NAA     100
#define BN_EPS  1e-5f
#define GROWS   96

typedef unsigned short u16;

__device__ __forceinline__ float b2f(u16 u) {
    union { uint32_t i; float f; } v; v.i = ((uint32_t)u) << 16; return v.f;
}
__device__ __forceinline__ u16 f2b(float f) {
    __hip_bfloat16 h = __float2bfloat16(f);
    return *(u16*)&h;
}
// branchless fast softplus: max(x,0) + log(1 + exp(-|x|))
__device__ __forceinline__ float sp_f(float x) {
    return fmaxf(x, 0.f) + __logf(1.f + __expf(-fabsf(x)));
}
__device__ __forceinline__ float sigm_f(float x) {
    return __builtin_amdgcn_rcpf(1.f + __expf(-x));
}

// ---------------- output 1: atom_fea * mask (fp32) ----------------
__global__ void k_mask(const float* __restrict__ atom, const float* __restrict__ mask,
                       float* __restrict__ dout) {
    int i = blockIdx.x * blockDim.x + threadIdx.x;
    int stride = gridDim.x * blockDim.x;
    for (; i < NN * ORIGF; i += stride) {
        int k = i % ORIGF;
        dout[BBC + i] = atom[i] * mask[k];
    }
}

// ---------------- h = (atom*mask) @ emb_W^T  (bf16 out) ----------------
// waves_per_eu(2,3): cap occupancy at 3 waves/SIMD -> ~170 VGPR budget so the
// 92 loop-invariant weight VGPRs stay resident (no rematerialized reloads).
__global__ __launch_bounds__(256) __attribute__((amdgpu_waves_per_eu(2, 3)))
void k_emb(const float* __restrict__ atom,
           const float* __restrict__ mask,
           const float* __restrict__ embW,
           u16* __restrict__ h) {
    __shared__ float xs[4 * 96];
    int lane = threadIdx.x & 63;
    int w = threadIdx.x >> 6;
    float wr[ORIGF];
#pragma unroll
    for (int k = 0; k < ORIGF; ++k) wr[k] = embW[lane * ORIGF + k];
    float m1 = mask[lane];
    float m2 = (lane < ORIGF - 64) ? mask[64 + lane] : 0.f;
    for (int base = blockIdx.x * 4; base < NN; base += gridDim.x * 4) {
        int n = base + w;   // NN % 4 == 0
        xs[w * 96 + lane] = atom[(size_t)n * ORIGF + lane] * m1;
        if (lane < ORIGF - 64)
            xs[w * 96 + 64 + lane] = atom[(size_t)n * ORIGF + 64 + lane] * m2;
        __syncthreads();
        float acc = 0.f;
#pragma unroll
        for (int k4 = 0; k4 < ORIGF / 4; ++k4) {
            float4 f = *(const float4*)&xs[w * 96 + 4 * k4];
            acc += f.x * wr[4*k4] + f.y * wr[4*k4+1] + f.z * wr[4*k4+2] + f.w * wr[4*k4+3];
        }
        h[(size_t)n * AFD + lane] = f2b(acc);
        __syncthreads();
    }
}

// ------- C (bf16 pairs): (h@Wc^T | h@Wn^T) -------
// u32 word layout: C32[n*128 + lane]      = (C1[ch=lane], C1[ch=lane+64])
//                  C32[n*128 + 64 + lane] = (C2[ch=lane], C2[ch=lane+64])
__global__ __launch_bounds__(256) __attribute__((amdgpu_waves_per_eu(2, 3)))
void k_cn(const u16* __restrict__ h,
          const float* __restrict__ convW,
          uint32_t* __restrict__ C32) {
    __shared__ float xs[2 * AFD];
    int lane = threadIdx.x & 63;
    int w = threadIdx.x >> 6;
    int half = w & 1;
    int sub = w >> 1;
    int koff = half * AFD;
    float wa[AFD], wb[AFD];
#pragma unroll
    for (int k = 0; k < AFD; ++k) {
        wa[k] = convW[lane * KTOT + koff + k];
        wb[k] = convW[(lane + 64) * KTOT + koff + k];
    }
    for (int base = blockIdx.x * 2; base < NN; base += gridDim.x * 2) {
        int n = base + sub;   // NN % 2 == 0
        if (half == 0) xs[sub * AFD + lane] = b2f(h[(size_t)n * AFD + lane]);
        __syncthreads();
        float aa = 0.f, ab = 0.f;
#pragma unroll
        for (int k4 = 0; k4 < AFD / 4; ++k4) {
            float4 f = *(const float4*)&xs[sub * AFD + 4 * k4];
            aa += f.x * wa[4*k4] + f.y * wa[4*k4+1] + f.z * wa[4*k4+2] + f.w * wa[4*k4+3];
            ab += f.x * wb[4*k4] + f.y * wb[4*k4+1] + f.z * wb[4*k4+2] + f.w * wb[4*k4+3];
        }
        C32[(size_t)n * 128 + half * 64 + lane] = (uint32_t)f2b(aa) | ((uint32_t)f2b(ab) << 16);
        __syncthreads();
    }
}

// stage 96 fp32 rows of nbr_fea into fs[row*44 + k]
__device__ __forceinline__ void stage_nbrf(const float* nbrf, int r0, float* fs) {
    const float4* src = (const float4*)(nbrf + (size_t)r0 * NBRF);
    for (int t = threadIdx.x; t < (GROWS * NBRF) / 4; t += 256) {
        float4 f = src[t];
        float vals[4] = {f.x, f.y, f.z, f.w};
#pragma unroll
        for (int j = 0; j < 4; ++j) {
            int e = t * 4 + j;
            int row = e / NBRF;
            int k = e - row * NBRF;
            fs[row * 44 + k] = vals[j];
        }
    }
}

// dual 41-wide dot against LDS row
__device__ __forceinline__ void edge_dot(const float* fr, const float* wfa,
                                         const float* wfb, float& aa, float& ab) {
#pragma unroll
    for (int k4 = 0; k4 < 10; ++k4) {
        float4 f = *(const float4*)&fr[4 * k4];
        aa += f.x * wfa[4*k4] + f.y * wfa[4*k4+1] + f.z * wfa[4*k4+2] + f.w * wfa[4*k4+3];
        ab += f.x * wfb[4*k4] + f.y * wfb[4*k4+1] + f.z * wfb[4*k4+2] + f.w * wfb[4*k4+3];
    }
    aa += fr[40] * wfa[40];
    ab += fr[40] * wfb[40];
}

// ------- pass 1: BN1 sum/sumsq stats over gated (no materialization) -------
__global__ __launch_bounds__(256) __attribute__((amdgpu_waves_per_eu(2, 3)))
void k_gs(
    const uint32_t* __restrict__ C32, const float* __restrict__ nbrf,
    const int* __restrict__ nbridx, const float* __restrict__ convW,
    const float* __restrict__ convb, float* __restrict__ stats)
{
    __shared__ float fs[GROWS * 44];
    __shared__ float red[4][64][4];
    int lane = threadIdx.x & 63;
    int w = threadIdx.x >> 6;
    int r0 = blockIdx.x * GROWS;
    stage_nbrf(nbrf, r0, fs);
    float wfa[NBRF], wfb[NBRF];
#pragma unroll
    for (int k = 0; k < NBRF; ++k) {
        wfa[k] = convW[lane * KTOT + 128 + k];
        wfb[k] = convW[(lane + 64) * KTOT + 128 + k];
    }
    float biasa = convb[lane], biasb = convb[64 + lane];
    __syncthreads();
    float suma = 0.f, sqa = 0.f, sumb = 0.f, sqb = 0.f;
    for (int rr = 0; rr < 24; ++rr) {
        int rl = w * 24 + rr;
        int r = r0 + rl;
        int n = r / MMN;
        int j = nbridx[r];
        uint32_t p1 = C32[(size_t)n * 128 + lane];
        uint32_t p2 = C32[(size_t)j * 128 + 64 + lane];
        float aa = b2f((u16)p1) + b2f((u16)p2) + biasa;
        float ab = b2f((u16)(p1 >> 16)) + b2f((u16)(p2 >> 16)) + biasb;
        edge_dot(&fs[rl * 44], wfa, wfb, aa, ab);
        suma += aa; sqa += aa * aa; sumb += ab; sqb += ab * ab;
    }
    red[w][lane][0] = suma; red[w][lane][1] = sqa;
    red[w][lane][2] = sumb; red[w][lane][3] = sqb;
    __syncthreads();
    if (threadIdx.x < 64) {
        int c = threadIdx.x;
        float a = 0, b = 0, cc = 0, d = 0;
#pragma unroll
        for (int ww = 0; ww < 4; ++ww) {
            a += red[ww][c][0]; b += red[ww][c][1];
            cc += red[ww][c][2]; d += red[ww][c][3];
        }
        atomicAdd(&stats[c], a);
        atomicAdd(&stats[64 + c], cc);
        atomicAdd(&stats[128 + c], b);
        atomicAdd(&stats[192 + c], d);
    }
}

// ------- finalize BN: scale/shift from sums -------
__global__ void k_fin(float* __restrict__ stats, const float* __restrict__ gg,
                      const float* __restrict__ bb, int nch, float invcnt,
                      int sumoff, int sqoff, int scoff, int shoff) {
    int c = threadIdx.x;
    if (c < nch) {
        float mean = stats[sumoff + c] * invcnt;
        float var  = fmaxf(stats[sqoff + c] * invcnt - mean * mean, 0.f);
        float sc   = gg[c] * rsqrtf(var + BN_EPS);
        stats[scoff + c] = sc;
        stats[shoff + c] = bb[c] - mean * sc;
    }
}

// ------- pass 2: recompute gated edge-sequentially, BN1 affine +
//         sigmoid*softplus, accumulate over m, store summed (bf16),
//         accumulate BN2 stats -------
__global__ __launch_bounds__(256) __attribute__((amdgpu_waves_per_eu(2, 3)))
void k_act(
    const uint32_t* __restrict__ C32, const float* __restrict__ nbrf,
    const int* __restrict__ nbridx, const float* __restrict__ convW,
    const float* __restrict__ convb, float* __restrict__ stats,
    u16* __restrict__ summed)
{
    __shared__ float fs[GROWS * 44];
    __shared__ float red[4][64][2];
    int lane = threadIdx.x & 63;
    int w = threadIdx.x >> 6;
    int r0 = blockIdx.x * GROWS;
    stage_nbrf(nbrf, r0, fs);
    float wfa[NBRF], wfb[NBRF];
#pragma unroll
    for (int k = 0; k < NBRF; ++k) {
        wfa[k] = convW[lane * KTOT + 128 + k];
        wfb[k] = convW[(lane + 64) * KTOT + 128 + k];
    }
    float biasa = convb[lane], biasb = convb[64 + lane];
    float sa = stats[384 + lane],      ba = stats[512 + lane];
    float sb = stats[384 + 64 + lane], bb = stats[512 + 64 + lane];
    __syncthreads();
    float s2 = 0.f, q2 = 0.f;
    float s = 0.f;
    float c1a = 0.f, c1b = 0.f;
    for (int rr = 0; rr < 24; ++rr) {
        int rl = w * 24 + rr;
        int r = r0 + rl;
        if ((rr % MMN) == 0) {              // new atom: 12 rows share n
            int n = r / MMN;
            uint32_t p1 = C32[(size_t)n * 128 + lane];
            c1a = b2f((u16)p1); c1b = b2f((u16)(p1 >> 16));
            s = 0.f;
        }
        int j = nbridx[r];
        uint32_t p2 = C32[(size_t)j * 128 + 64 + lane];
        float aa = c1a + b2f((u16)p2) + biasa;
        float ab = c1b + b2f((u16)(p2 >> 16)) + biasb;
        edge_dot(&fs[rl * 44], wfa, wfb, aa, ab);
        float f1 = aa * sa + ba;
        float cc = ab * sb + bb;
        s += sigm_f(f1) * sp_f(cc);
        if ((rr % MMN) == MMN - 1) {        // flush atom
            int n = r / MMN;
            summed[(size_t)n * AFD + lane] = f2b(s);
            s2 += s; q2 += s * s;
        }
    }
    red[w][lane][0] = s2; red[w][lane][1] = q2;
    __syncthreads();
    if (threadIdx.x < 64) {
        int c = threadIdx.x;
        float a = 0, b = 0;
#pragma unroll
        for (int ww = 0; ww < 4; ++ww) { a += red[ww][c][0]; b += red[ww][c][1]; }
        atomicAdd(&stats[256 + c], a);
        atomicAdd(&stats[320 + c], b);
    }
}

// ------- h = softplus(h + BN2(summed))  (bf16 h) -------
__global__ void k_update(u16* __restrict__ h, const u16* __restrict__ summed,
                         const float* __restrict__ stats) {
    int i = blockIdx.x * blockDim.x + threadIdx.x;
    int st = gridDim.x * blockDim.x;
    int c = threadIdx.x & 63;
    float sc = stats[640 + c], sh = stats[704 + c];
    for (; i < NN * AFD; i += st) {
        float x = b2f(h[i]) + b2f(summed[i]) * sc + sh;
        h[i] = f2b(sp_f(x));
    }
}

// ------- row-normalize + mean-pool per crystal -------
__global__ __launch_bounds__(256) void k_pool(const u16* __restrict__ h,
                                              const int* __restrict__ cry,
                                              float* __restrict__ pooled) {
    __shared__ float red[4][64];
    int lane = threadIdx.x & 63, w = threadIdx.x >> 6;
    int b = blockIdx.x;
    float acc = 0.f;
    for (int a = w; a < NAA; a += 4) {
        int idx = cry[b * NAA + a];
        float v = b2f(h[(size_t)idx * AFD + lane]);
        float s2 = v * v;
#pragma unroll
        for (int o = 32; o > 0; o >>= 1) s2 += __shfl_xor(s2, o, 64);
        acc += v / fmaxf(sqrtf(s2), 1e-12f);
    }
    red[w][lane] = acc;
    __syncthreads();
    if (threadIdx.x < 64) {
        float s = red[0][threadIdx.x] + red[1][threadIdx.x] +
                  red[2][threadIdx.x] + red[3][threadIdx.x];
        pooled[b * AFD + threadIdx.x] = s * (1.f / NAA);
    }
}

// ------- MLP head (fp32 out) -------
__global__ __launch_bounds__(64) void k_head(const float* __restrict__ pooled,
    const float* __restrict__ fc1W, const float* __restrict__ fc1b,
    const float* __restrict__ fc2W, const float* __restrict__ fc2b,
    const float* __restrict__ outW, const float* __restrict__ outb,
    float* __restrict__ props) {
    __shared__ float W1[64 * 65], W2[64 * 65], zbuf[64], pbuf[64];
    int l = threadIdx.x;
    for (int e = l; e < 64 * 64; e += 64) {
        int o = e >> 6, k = e & 63;
        W1[o * 65 + k] = fc1W[e];
        W2[o * 65 + k] = fc2W[e];
    }
    int b = blockIdx.x;
    pbuf[l] = pooled[b * AFD + l];
    __syncthreads();
    float acc = fc1b[l];
#pragma unroll
    for (int k = 0; k < 64; ++k) acc += pbuf[k] * W1[l * 65 + k];
    zbuf[l] = sp_f(acc);
    __syncthreads();
    acc = fc2b[l];
#pragma unroll
    for (int k = 0; k < 64; ++k) acc += zbuf[k] * W2[l * 65 + k];
    float v = sp_f(acc) * outW[l];
#pragma unroll
    for (int o = 32; o > 0; o >>= 1) v += __shfl_xor(v, o, 64);
    if (l == 0) props[b] = v + outb[0];
}

extern "C" void kernel_launch(void* const* d_in, const int* in_sizes, int n_in,
                              void* d_out, int out_size, void* d_ws, size_t ws_size,
                              hipStream_t stream) {
    const float* atom  = (const float*)d_in[0];
    const float* nbrf  = (const float*)d_in[1];
    const int* nbridx  = (const int*)d_in[2];
    const int* cry     = (const int*)d_in[3];
    const float* mask  = (const float*)d_in[4];
    const float* embW  = (const float*)d_in[5];
    const float* convW = (const float*)d_in[6];
    const float* convb = (const float*)d_in[7];
    const float* bn1g  = (const float*)d_in[8];
    const float* bn1b  = (const float*)d_in[9];
    const float* bn2g  = (const float*)d_in[10];
    const float* bn2b  = (const float*)d_in[11];
    const float* fc1W  = (const float*)d_in[12];
    const float* fc1b  = (const float*)d_in[13];
    const float* fc2W  = (const float*)d_in[14];
    const float* fc2b  = (const float*)d_in[15];
    const float* outW  = (const float*)d_in[16];
    const float* outb  = (const float*)d_in[17];

    char* ws = (char*)d_ws;
    float* stats    = (float*)ws;                      // 768 floats
    float* pooled   = (float*)(ws + 4096);             // 128,000 B
    u16*   h        = (u16*)(ws + (1u << 20));         // 6.4 MB
    u16*   summed   = (u16*)(ws + (8u << 20));         // 6.4 MB
    uint32_t* C32   = (uint32_t*)(ws + (16u << 20));   // 25.6 MB

    float* out_props = (float*)d_out;

    k_mask<<<2048, 256, 0, stream>>>(atom, mask, (float*)d_out);
    k_emb<<<512, 256, 0, stream>>>(atom, mask, embW, h);
    for (int i = 0; i < 3; ++i) {
        hipMemsetAsync(stats, 0, 384 * sizeof(float), stream);
        k_cn<<<1024, 256, 0, stream>>>(h, convW + (size_t)i * GCH * KTOT, C32);
        k_gs<<<NMROWS / GROWS, 256, 0, stream>>>(C32, nbrf, nbridx,
            convW + (size_t)i * GCH * KTOT, convb + (size_t)i * GCH, stats);
        k_fin<<<1, 128, 0, stream>>>(stats, bn1g + (size_t)i * GCH, bn1b + (size_t)i * GCH,
                                     128, 1.f / NMROWS, 0, 128, 384, 512);
        k_act<<<NMROWS / GROWS, 256, 0, stream>>>(C32, nbrf, nbridx,
            convW + (size_t)i * GCH * KTOT, convb + (size_t)i * GCH, stats, summed);
        k_fin<<<1, 128, 0, stream>>>(stats, bn2g + (size_t)i * AFD, bn2b + (size_t)i * AFD,
                                     64, 1.f / NN, 256, 320, 640, 704);
        k_update<<<1024, 256, 0, stream>>>(h, summed, stats);
    }
    k_pool<<<BBC, 256, 0, stream>>>(h, cry, pooled);
    k_head<<<BBC, 64, 0, stream>>>(pooled, fc1W, fc1b, fc2W, fc2b, outW, outb, out_props);
}

// Round 8
// 1344.709 us; speedup vs baseline: 1.3462x; 1.3462x over previous
//
#include <hip/hip_runtime.h>
#include <hip/hip_bf16.h>
#include <stdint.h>

#define NN      50000
#define MMN     12
#define NMROWS  600000
#define ORIGF   92
#define NBRF    41
#define AFD     64
#define GCH     128
#define KTOT    169
#define BBC     500
#define NAA     100
#define BN_EPS  1e-5f
#define GROWS   96

typedef unsigned short u16;

__device__ __forceinline__ float b2f(u16 u) {
    union { uint32_t i; float f; } v; v.i = ((uint32_t)u) << 16; return v.f;
}
__device__ __forceinline__ u16 f2b(float f) {
    __hip_bfloat16 h = __float2bfloat16(f);
    return *(u16*)&h;
}
// branchless fast softplus: max(x,0) + log(1 + exp(-|x|))
__device__ __forceinline__ float sp_f(float x) {
    return fmaxf(x, 0.f) + __logf(1.f + __expf(-fabsf(x)));
}
__device__ __forceinline__ float sigm_f(float x) {
    return __builtin_amdgcn_rcpf(1.f + __expf(-x));
}

// ---------------- output 1: atom_fea * mask (fp32) ----------------
__global__ void k_mask(const float* __restrict__ atom, const float* __restrict__ mask,
                       float* __restrict__ dout) {
    int i = blockIdx.x * blockDim.x + threadIdx.x;
    int stride = gridDim.x * blockDim.x;
    for (; i < NN * ORIGF; i += stride) {
        int k = i % ORIGF;
        dout[BBC + i] = atom[i] * mask[k];
    }
}

// ---------------- h = (atom*mask) @ emb_W^T  (bf16 out) ----------------
__global__ __launch_bounds__(256, 2) void k_emb(const float* __restrict__ atom,
                                                const float* __restrict__ mask,
                                                const float* __restrict__ embW,
                                                u16* __restrict__ h) {
    __shared__ float xs[4 * 96];
    int lane = threadIdx.x & 63;
    int w = threadIdx.x >> 6;
    float wr[ORIGF];
#pragma unroll
    for (int k = 0; k < ORIGF; ++k) wr[k] = embW[lane * ORIGF + k];
    float m1 = mask[lane];
    float m2 = (lane < ORIGF - 64) ? mask[64 + lane] : 0.f;
    for (int base = blockIdx.x * 4; base < NN; base += gridDim.x * 4) {
        int n = base + w;   // NN % 4 == 0
        xs[w * 96 + lane] = atom[(size_t)n * ORIGF + lane] * m1;
        if (lane < ORIGF - 64)
            xs[w * 96 + 64 + lane] = atom[(size_t)n * ORIGF + 64 + lane] * m2;
        __syncthreads();
        float acc = 0.f;
#pragma unroll
        for (int k4 = 0; k4 < ORIGF / 4; ++k4) {
            float4 f = *(const float4*)&xs[w * 96 + 4 * k4];
            acc += f.x * wr[4*k4] + f.y * wr[4*k4+1] + f.z * wr[4*k4+2] + f.w * wr[4*k4+3];
        }
        h[(size_t)n * AFD + lane] = f2b(acc);
        __syncthreads();
    }
}

// ------- C (bf16 pairs): (h@Wc^T | h@Wn^T) -------
// u32 word layout: C32[n*128 + lane]      = (C1[ch=lane], C1[ch=lane+64])
//                  C32[n*128 + 64 + lane] = (C2[ch=lane], C2[ch=lane+64])
__global__ __launch_bounds__(256, 2) void k_cn(const u16* __restrict__ h,
                                               const float* __restrict__ convW,
                                               uint32_t* __restrict__ C32) {
    __shared__ float xs[2 * AFD];
    int lane = threadIdx.x & 63;
    int w = threadIdx.x >> 6;
    int half = w & 1;
    int sub = w >> 1;
    int koff = half * AFD;
    float wa[AFD], wb[AFD];
#pragma unroll
    for (int k = 0; k < AFD; ++k) {
        wa[k] = convW[lane * KTOT + koff + k];
        wb[k] = convW[(lane + 64) * KTOT + koff + k];
    }
    for (int base = blockIdx.x * 2; base < NN; base += gridDim.x * 2) {
        int n = base + sub;   // NN % 2 == 0
        if (half == 0) xs[sub * AFD + lane] = b2f(h[(size_t)n * AFD + lane]);
        __syncthreads();
        float aa = 0.f, ab = 0.f;
#pragma unroll
        for (int k4 = 0; k4 < AFD / 4; ++k4) {
            float4 f = *(const float4*)&xs[sub * AFD + 4 * k4];
            aa += f.x * wa[4*k4] + f.y * wa[4*k4+1] + f.z * wa[4*k4+2] + f.w * wa[4*k4+3];
            ab += f.x * wb[4*k4] + f.y * wb[4*k4+1] + f.z * wb[4*k4+2] + f.w * wb[4*k4+3];
        }
        C32[(size_t)n * 128 + half * 64 + lane] = (uint32_t)f2b(aa) | ((uint32_t)f2b(ab) << 16);
        __syncthreads();
    }
}

// stage 96 fp32 rows of nbr_fea into fs[row*44 + k]
__device__ __forceinline__ void stage_nbrf(const float* nbrf, int r0, float* fs) {
    const float4* src = (const float4*)(nbrf + (size_t)r0 * NBRF);
    for (int t = threadIdx.x; t < (GROWS * NBRF) / 4; t += 256) {
        float4 f = src[t];
        float vals[4] = {f.x, f.y, f.z, f.w};
#pragma unroll
        for (int j = 0; j < 4; ++j) {
            int e = t * 4 + j;
            int row = e / NBRF;
            int k = e - row * NBRF;
            fs[row * 44 + k] = vals[j];
        }
    }
}

// ------- pass 1: gated rows, channel-split across waves -------
// wave w: h = w&1 (channel half), rg = w>>1 (row group, 48 rows each).
// Each lane holds 41 weights (one channel) -> live set ~56 VGPR, no remat.
// STORE: also materialize gated (bf16) for the streaming k_acts pass.
template<bool STORE>
__global__ __launch_bounds__(256) void k_gs2(
    const uint32_t* __restrict__ C32, const float* __restrict__ nbrf,
    const int* __restrict__ nbridx, const float* __restrict__ convW,
    const float* __restrict__ convb, float* __restrict__ stats,
    u16* __restrict__ gated)
{
    __shared__ float fs[GROWS * 44];
    __shared__ float red[4][64][2];
    int lane = threadIdx.x & 63;
    int w = threadIdx.x >> 6;
    int h = w & 1;
    int rg = w >> 1;
    int ch = h * 64 + lane;
    int sh = h * 16;
    int r0 = blockIdx.x * GROWS;
    stage_nbrf(nbrf, r0, fs);
    float wf[NBRF];
#pragma unroll
    for (int k = 0; k < NBRF; ++k) wf[k] = convW[ch * KTOT + 128 + k];
    float bias = convb[ch];
    __syncthreads();
    float sum = 0.f, sq = 0.f;
    for (int rr = 0; rr < 48; ++rr) {
        int rl = rg * 48 + rr;
        int r = r0 + rl;
        int n = r / MMN;
        int j = nbridx[r];
        uint32_t p1 = C32[(size_t)n * 128 + lane];
        uint32_t p2 = C32[(size_t)j * 128 + 64 + lane];
        float g = b2f((u16)(p1 >> sh)) + b2f((u16)(p2 >> sh)) + bias;
        const float* fr = &fs[rl * 44];
#pragma unroll
        for (int k4 = 0; k4 < 10; ++k4) {
            float4 f = *(const float4*)&fr[4 * k4];
            g += f.x * wf[4*k4] + f.y * wf[4*k4+1] + f.z * wf[4*k4+2] + f.w * wf[4*k4+3];
        }
        g += fr[40] * wf[40];
        if (STORE) gated[(size_t)r * GCH + ch] = f2b(g);
        sum += g; sq += g * g;
    }
    red[w][lane][0] = sum; red[w][lane][1] = sq;
    __syncthreads();
    if (threadIdx.x < 128) {
        int hh = threadIdx.x >> 6;
        int c = threadIdx.x & 63;
        float a = red[hh][c][0] + red[hh + 2][c][0];
        float b = red[hh][c][1] + red[hh + 2][c][1];
        atomicAdd(&stats[hh * 64 + c], a);
        atomicAdd(&stats[128 + hh * 64 + c], b);
    }
}

// ------- finalize BN: scale/shift from sums -------
__global__ void k_fin(float* __restrict__ stats, const float* __restrict__ gg,
                      const float* __restrict__ bb, int nch, float invcnt,
                      int sumoff, int sqoff, int scoff, int shoff) {
    int c = threadIdx.x;
    if (c < nch) {
        float mean = stats[sumoff + c] * invcnt;
        float var  = fmaxf(stats[sqoff + c] * invcnt - mean * mean, 0.f);
        float sc   = gg[c] * rsqrtf(var + BN_EPS);
        stats[scoff + c] = sc;
        stats[shoff + c] = bb[c] - mean * sc;
    }
}

// ------- pass 2 (Path A): stream materialized gated -------
__global__ __launch_bounds__(256) void k_acts(
    const u16* __restrict__ gated, float* __restrict__ stats,
    u16* __restrict__ summed)
{
    __shared__ float red[4][64][2];
    int lane = threadIdx.x & 63;
    int w = threadIdx.x >> 6;
    float sa = stats[384 + lane],      ba = stats[512 + lane];
    float sb = stats[384 + 64 + lane], bb = stats[512 + 64 + lane];
    int wave = blockIdx.x * 4 + w, nw = gridDim.x * 4;
    float s2 = 0.f, q2 = 0.f;
    for (int n = wave; n < NN; n += nw) {
        const u16* gr = gated + (size_t)n * MMN * GCH;
        float s = 0.f;
#pragma unroll
        for (int m = 0; m < MMN; ++m) {
            float f1 = b2f(gr[m * GCH + lane]) * sa + ba;
            float cc = b2f(gr[m * GCH + 64 + lane]) * sb + bb;
            s += sigm_f(f1) * sp_f(cc);
        }
        summed[(size_t)n * AFD + lane] = f2b(s);
        s2 += s; q2 += s * s;
    }
    red[w][lane][0] = s2; red[w][lane][1] = q2;
    __syncthreads();
    if (threadIdx.x < 64) {
        int c = threadIdx.x;
        float a = 0, b = 0;
#pragma unroll
        for (int ww = 0; ww < 4; ++ww) { a += red[ww][c][0]; b += red[ww][c][1]; }
        atomicAdd(&stats[256 + c], a);
        atomicAdd(&stats[320 + c], b);
    }
}

// dual 41-wide dot against LDS row (Path B fallback)
__device__ __forceinline__ void edge_dot(const float* fr, const float* wfa,
                                         const float* wfb, float& aa, float& ab) {
#pragma unroll
    for (int k4 = 0; k4 < 10; ++k4) {
        float4 f = *(const float4*)&fr[4 * k4];
        aa += f.x * wfa[4*k4] + f.y * wfa[4*k4+1] + f.z * wfa[4*k4+2] + f.w * wfa[4*k4+3];
        ab += f.x * wfb[4*k4] + f.y * wfb[4*k4+1] + f.z * wfb[4*k4+2] + f.w * wfb[4*k4+3];
    }
    aa += fr[40] * wfa[40];
    ab += fr[40] * wfb[40];
}

// ------- pass 2 (Path B fallback): recompute gated edge-sequentially -------
__global__ __launch_bounds__(256) void k_act(
    const uint32_t* __restrict__ C32, const float* __restrict__ nbrf,
    const int* __restrict__ nbridx, const float* __restrict__ convW,
    const float* __restrict__ convb, float* __restrict__ stats,
    u16* __restrict__ summed)
{
    __shared__ float fs[GROWS * 44];
    __shared__ float red[4][64][2];
    int lane = threadIdx.x & 63;
    int w = threadIdx.x >> 6;
    int r0 = blockIdx.x * GROWS;
    stage_nbrf(nbrf, r0, fs);
    float wfa[NBRF], wfb[NBRF];
#pragma unroll
    for (int k = 0; k < NBRF; ++k) {
        wfa[k] = convW[lane * KTOT + 128 + k];
        wfb[k] = convW[(lane + 64) * KTOT + 128 + k];
    }
    float biasa = convb[lane], biasb = convb[64 + lane];
    float sa = stats[384 + lane],      ba = stats[512 + lane];
    float sb = stats[384 + 64 + lane], bb = stats[512 + 64 + lane];
    __syncthreads();
    float s2 = 0.f, q2 = 0.f;
    float s = 0.f;
    float c1a = 0.f, c1b = 0.f;
    for (int rr = 0; rr < 24; ++rr) {
        int rl = w * 24 + rr;
        int r = r0 + rl;
        if ((rr % MMN) == 0) {
            int n = r / MMN;
            uint32_t p1 = C32[(size_t)n * 128 + lane];
            c1a = b2f((u16)p1); c1b = b2f((u16)(p1 >> 16));
            s = 0.f;
        }
        int j = nbridx[r];
        uint32_t p2 = C32[(size_t)j * 128 + 64 + lane];
        float aa = c1a + b2f((u16)p2) + biasa;
        float ab = c1b + b2f((u16)(p2 >> 16)) + biasb;
        edge_dot(&fs[rl * 44], wfa, wfb, aa, ab);
        float f1 = aa * sa + ba;
        float cc = ab * sb + bb;
        s += sigm_f(f1) * sp_f(cc);
        if ((rr % MMN) == MMN - 1) {
            int n = r / MMN;
            summed[(size_t)n * AFD + lane] = f2b(s);
            s2 += s; q2 += s * s;
        }
    }
    red[w][lane][0] = s2; red[w][lane][1] = q2;
    __syncthreads();
    if (threadIdx.x < 64) {
        int c = threadIdx.x;
        float a = 0, b = 0;
#pragma unroll
        for (int ww = 0; ww < 4; ++ww) { a += red[ww][c][0]; b += red[ww][c][1]; }
        atomicAdd(&stats[256 + c], a);
        atomicAdd(&stats[320 + c], b);
    }
}

// ------- h = softplus(h + BN2(summed))  (bf16 h) -------
__global__ void k_update(u16* __restrict__ h, const u16* __restrict__ summed,
                         const float* __restrict__ stats) {
    int i = blockIdx.x * blockDim.x + threadIdx.x;
    int st = gridDim.x * blockDim.x;
    int c = threadIdx.x & 63;
    float sc = stats[640 + c], shf = stats[704 + c];
    for (; i < NN * AFD; i += st) {
        float x = b2f(h[i]) + b2f(summed[i]) * sc + shf;
        h[i] = f2b(sp_f(x));
    }
}

// ------- row-normalize + mean-pool per crystal -------
__global__ __launch_bounds__(256) void k_pool(const u16* __restrict__ h,
                                              const int* __restrict__ cry,
                                              float* __restrict__ pooled) {
    __shared__ float red[4][64];
    int lane = threadIdx.x & 63, w = threadIdx.x >> 6;
    int b = blockIdx.x;
    float acc = 0.f;
    for (int a = w; a < NAA; a += 4) {
        int idx = cry[b * NAA + a];
        float v = b2f(h[(size_t)idx * AFD + lane]);
        float s2 = v * v;
#pragma unroll
        for (int o = 32; o > 0; o >>= 1) s2 += __shfl_xor(s2, o, 64);
        acc += v / fmaxf(sqrtf(s2), 1e-12f);
    }
    red[w][lane] = acc;
    __syncthreads();
    if (threadIdx.x < 64) {
        float s = red[0][threadIdx.x] + red[1][threadIdx.x] +
                  red[2][threadIdx.x] + red[3][threadIdx.x];
        pooled[b * AFD + threadIdx.x] = s * (1.f / NAA);
    }
}

// ------- MLP head (fp32 out) -------
__global__ __launch_bounds__(64) void k_head(const float* __restrict__ pooled,
    const float* __restrict__ fc1W, const float* __restrict__ fc1b,
    const float* __restrict__ fc2W, const float* __restrict__ fc2b,
    const float* __restrict__ outW, const float* __restrict__ outb,
    float* __restrict__ props) {
    __shared__ float W1[64 * 65], W2[64 * 65], zbuf[64], pbuf[64];
    int l = threadIdx.x;
    for (int e = l; e < 64 * 64; e += 64) {
        int o = e >> 6, k = e & 63;
        W1[o * 65 + k] = fc1W[e];
        W2[o * 65 + k] = fc2W[e];
    }
    int b = blockIdx.x;
    pbuf[l] = pooled[b * AFD + l];
    __syncthreads();
    float acc = fc1b[l];
#pragma unroll
    for (int k = 0; k < 64; ++k) acc += pbuf[k] * W1[l * 65 + k];
    zbuf[l] = sp_f(acc);
    __syncthreads();
    acc = fc2b[l];
#pragma unroll
    for (int k = 0; k < 64; ++k) acc += zbuf[k] * W2[l * 65 + k];
    float v = sp_f(acc) * outW[l];
#pragma unroll
    for (int o = 32; o > 0; o >>= 1) v += __shfl_xor(v, o, 64);
    if (l == 0) props[b] = v + outb[0];
}

extern "C" void kernel_launch(void* const* d_in, const int* in_sizes, int n_in,
                              void* d_out, int out_size, void* d_ws, size_t ws_size,
                              hipStream_t stream) {
    const float* atom  = (const float*)d_in[0];
    const float* nbrf  = (const float*)d_in[1];
    const int* nbridx  = (const int*)d_in[2];
    const int* cry     = (const int*)d_in[3];
    const float* mask  = (const float*)d_in[4];
    const float* embW  = (const float*)d_in[5];
    const float* convW = (const float*)d_in[6];
    const float* convb = (const float*)d_in[7];
    const float* bn1g  = (const float*)d_in[8];
    const float* bn1b  = (const float*)d_in[9];
    const float* bn2g  = (const float*)d_in[10];
    const float* bn2b  = (const float*)d_in[11];
    const float* fc1W  = (const float*)d_in[12];
    const float* fc1b  = (const float*)d_in[13];
    const float* fc2W  = (const float*)d_in[14];
    const float* fc2b  = (const float*)d_in[15];
    const float* outW  = (const float*)d_in[16];
    const float* outb  = (const float*)d_in[17];

    char* ws = (char*)d_ws;
    float* stats    = (float*)ws;                      // 768 floats
    float* pooled   = (float*)(ws + 4096);             // 128,000 B
    u16*   h        = (u16*)(ws + (1u << 20));         // 6.4 MB
    u16*   summed   = (u16*)(ws + (8u << 20));         // 6.4 MB
    uint32_t* C32   = (uint32_t*)(ws + (16u << 20));   // 25.6 MB
    u16*   gated    = (u16*)(ws + (48u << 20));        // 153.6 MB (Path A only)
    const bool bigws = ws_size >= (size_t)(48u << 20) + 153600000u;

    float* out_props = (float*)d_out;

    k_mask<<<2048, 256, 0, stream>>>(atom, mask, (float*)d_out);
    k_emb<<<512, 256, 0, stream>>>(atom, mask, embW, h);
    for (int i = 0; i < 3; ++i) {
        hipMemsetAsync(stats, 0, 384 * sizeof(float), stream);
        k_cn<<<1024, 256, 0, stream>>>(h, convW + (size_t)i * GCH * KTOT, C32);
        if (bigws)
            k_gs2<true><<<NMROWS / GROWS, 256, 0, stream>>>(C32, nbrf, nbridx,
                convW + (size_t)i * GCH * KTOT, convb + (size_t)i * GCH, stats, gated);
        else
            k_gs2<false><<<NMROWS / GROWS, 256, 0, stream>>>(C32, nbrf, nbridx,
                convW + (size_t)i * GCH * KTOT, convb + (size_t)i * GCH, stats, gated);
        k_fin<<<1, 128, 0, stream>>>(stats, bn1g + (size_t)i * GCH, bn1b + (size_t)i * GCH,
                                     128, 1.f / NMROWS, 0, 128, 384, 512);
        if (bigws)
            k_acts<<<256, 256, 0, stream>>>(gated, stats, summed);
        else
            k_act<<<NMROWS / GROWS, 256, 0, stream>>>(C32, nbrf, nbridx,
                convW + (size_t)i * GCH * KTOT, convb + (size_t)i * GCH, stats, summed);
        k_fin<<<1, 128, 0, stream>>>(stats, bn2g + (size_t)i * AFD, bn2b + (size_t)i * AFD,
                                     64, 1.f / NN, 256, 320, 640, 704);
        k_update<<<1024, 256, 0, stream>>>(h, summed, stats);
    }
    k_pool<<<BBC, 256, 0, stream>>>(h, cry, pooled);
    k_head<<<BBC, 64, 0, stream>>>(pooled, fc1W, fc1b, fc2W, fc2b, outW, outb, out_props);
}